// Round 6
// baseline (646.086 us; speedup 1.0000x reference)
//
#include <hip/hip_runtime.h>

// ---------- sizes (hardcoded for this problem) ----------
#define BATCH 4
#define SEQ   4096
#define DMODEL 2048
#define NHEAD 16
#define DHEAD 128
#define MROWS (BATCH*SEQ)          // 16384
#define LC    128                  // scan chunk length
#define NCH   (SEQ/LC)             // 32 chunks

typedef unsigned short ushort_t;
typedef __bf16 v8bf __attribute__((ext_vector_type(8)));
typedef float  f32x4 __attribute__((ext_vector_type(4)));

__device__ __forceinline__ float b2f(ushort_t h) {
    return __uint_as_float(((unsigned)h) << 16);
}
__device__ __forceinline__ ushort_t f2b(float f) {
    unsigned u = __float_as_uint(f);
    return (ushort_t)((u + 0x7fffu + ((u >> 16) & 1u)) >> 16);
}

// ---------- cast fp32 -> bf16 (8 elem/thread, 16B loads+stores) ----------
__global__ void cast_f32_bf16(const float* __restrict__ in, ushort_t* __restrict__ out, int n) {
    int i = (blockIdx.x * blockDim.x + threadIdx.x) * 8;
    const int stride = gridDim.x * blockDim.x * 8;
    for (; i < n; i += stride) {
        float4 a = *(const float4*)(in + i);
        float4 b = *(const float4*)(in + i + 4);
        ushort_t o[8] = {f2b(a.x), f2b(a.y), f2b(a.z), f2b(a.w),
                         f2b(b.x), f2b(b.y), f2b(b.z), f2b(b.w)};
        *(uint4*)(out + i) = *(const uint4*)o;
    }
}

// 4 weight matrices in one launch (blockIdx.y selects)
__global__ void cast_weights(const float* __restrict__ w0, const float* __restrict__ w1,
                             const float* __restrict__ w2, const float* __restrict__ w3,
                             ushort_t* __restrict__ o0, ushort_t* __restrict__ o1,
                             ushort_t* __restrict__ o2, ushort_t* __restrict__ o3) {
    const int wsel = blockIdx.y;
    const float* src = wsel == 0 ? w0 : wsel == 1 ? w1 : wsel == 2 ? w2 : w3;
    ushort_t* dst    = wsel == 0 ? o0 : wsel == 1 ? o1 : wsel == 2 ? o2 : o3;
    const int n = DMODEL * DMODEL;
    int i = (blockIdx.x * blockDim.x + threadIdx.x) * 8;
    const int stride = gridDim.x * blockDim.x * 8;
    for (; i < n; i += stride) {
        float4 a = *(const float4*)(src + i);
        float4 b = *(const float4*)(src + i + 4);
        ushort_t o[8] = {f2b(a.x), f2b(a.y), f2b(a.z), f2b(a.w),
                         f2b(b.x), f2b(b.y), f2b(b.z), f2b(b.w)};
        *(uint4*)(dst + i) = *(const uint4*)o;
    }
}

// ======== 256x256 bf16 GEMM: conflict-free LDS layout + m201 8-barrier phase discipline ========
// C = A(MxK) * B(NxK)^T. 512 threads = 8 waves (2M x 4N), per-wave 128x64 out.
// LDS 128 KiB: [2 buf][ A:256x64 | B:256x64 ] bf16, row-major, 128B rows.
// Swizzle: physical 16B-slot-in-row = logical_slot ^ (row & 7) (conflict-free at 16- and
// 32-lane beat granularity). Dest linear, source pre-swizzled (involution both sides).
// Sync (m201): per K-tile 4 phases, each {ds-issue ; stage ; BAR ; lgkmcnt(0) ; setprio(1)
// 16xMFMA setprio(0) ; BAR}. vmcnt(2) counted once per K-tile at ph1 (never 0 in loop).

#define GLL(src, dstoff) __builtin_amdgcn_global_load_lds( \
    (const __attribute__((address_space(1))) void*)(src), \
    (__attribute__((address_space(3))) void*)((char*)lds + (dstoff)), 16, 0, 0)

#define STG_A(buf, half, kt) do { \
    GLL(pA + ((half) * 128 +  0) * (size_t)K + (kt), (buf) * 65536 + (half) * 16384 + wid * 1024); \
    GLL(pA + ((half) * 128 + 64) * (size_t)K + (kt), (buf) * 65536 + (half) * 16384 + wid * 1024 + 8192); } while (0)
#define STG_B(buf, half, kt) do { \
    GLL(pB + ((half) * 128 +  0) * (size_t)K + (kt), (buf) * 65536 + 32768 + (half) * 16384 + wid * 1024); \
    GLL(pB + ((half) * 128 + 64) * (size_t)K + (kt), (buf) * 65536 + 32768 + (half) * 16384 + wid * 1024 + 8192); } while (0)

#define DSA(buf, akk, mh) do { \
    const ushort_t* _p = lds + (buf) * 32768 + (akk) + (mh) * 4096; \
    abuf[0] = *(const v8bf*)_p;          abuf[1] = *(const v8bf*)(_p + 1024); \
    abuf[2] = *(const v8bf*)(_p + 2048); abuf[3] = *(const v8bf*)(_p + 3072); } while (0)
#define DSB(buf, bkk) do { \
    const ushort_t* _p = lds + (buf) * 32768 + (bkk); \
    bbuf[0] = *(const v8bf*)_p;          bbuf[1] = *(const v8bf*)(_p + 1024); \
    bbuf[2] = *(const v8bf*)(_p + 2048); bbuf[3] = *(const v8bf*)(_p + 3072); } while (0)

#define VMW(n) asm volatile("s_waitcnt vmcnt(" #n ")" ::: "memory")
#define BAR()  __builtin_amdgcn_s_barrier()

// {BAR ; lgkmcnt(0) ; setprio(1) 16xMFMA setprio(0) ; BAR}
#define MFMA_PH(mh) do { \
    __builtin_amdgcn_s_barrier(); \
    asm volatile("s_waitcnt lgkmcnt(0)" ::: "memory"); \
    __builtin_amdgcn_sched_barrier(0); \
    __builtin_amdgcn_s_setprio(1); \
    _Pragma("unroll") \
    for (int _m = 0; _m < 4; ++_m) \
        _Pragma("unroll") \
        for (int _n = 0; _n < 4; ++_n) \
            acc[(mh) * 4 + _m][_n] = __builtin_amdgcn_mfma_f32_16x16x32_bf16( \
                abuf[_m], bbuf[_n], acc[(mh) * 4 + _m][_n], 0, 0, 0); \
    __builtin_amdgcn_s_setprio(0); \
    __builtin_amdgcn_sched_barrier(0); \
    __builtin_amdgcn_s_barrier(); \
} while (0)

template<int N, int EPI>
__global__ __launch_bounds__(512, 2) void gemm8(const ushort_t* __restrict__ A,
                                                const ushort_t* __restrict__ Bm,
                                                ushort_t* __restrict__ o0,
                                                ushort_t* __restrict__ o1,
                                                ushort_t* __restrict__ o2,
                                                float* __restrict__ of) {
    constexpr int K  = DMODEL;
    constexpr int NT = K / 64;           // 32 K-tiles
    constexpr int NBN = N / 256;
    constexpr int NWG = (MROWS / 256) * NBN;
    extern __shared__ ushort_t lds[];    // 65536 ushorts = 128 KiB

    // XCD-bijective swizzle (NWG % 8 == 0 for both instantiations)
    int wg = blockIdx.x;
    wg = (wg & 7) * (NWG / 8) + (wg >> 3);
    const int tm = (wg / NBN) * 256;
    const int tn = (wg % NBN) * 256;

    const int tid  = threadIdx.x;
    const int lane = tid & 63;
    const int wid  = tid >> 6;           // 8 waves
    const int wr   = wid >> 2;           // 0..1 (M half)
    const int wc   = wid & 3;            // 0..3 (N quarter)

    // ---- staging source base (per-lane, pre-swizzled; dest stays linear) ----
    // dest row = half*128 + j*64 + wid*8 + (lane>>3); phys slot-in-row = lane&7
    // -> logical slot = (lane&7) ^ ((lane>>3)&7)
    const int rs = wid * 8 + (lane >> 3);
    const int cs = ((lane & 7) ^ ((lane >> 3) & 7)) * 8;
    const ushort_t* pA = A  + (size_t)(tm + rs) * K + cs;
    const ushort_t* pB = Bm + (size_t)(tn + rs) * K + cs;

    // ---- fragment ds_read bases (ushort units) ----
    // logical slot = kk*4 + q (q = lane>>4); physical = logical ^ (l4 & 7)
    const int q  = lane >> 4;
    const int l4 = lane & 15;
    const int sx = l4 & 7;
    const int abase0 = (wr * 128 + l4) * 64 + ((q ^ sx)) * 8;
    const int abase1 = (wr * 128 + l4) * 64 + (((4 + q) ^ sx)) * 8;
    const int bbase0 = 16384 + (wc * 64 + l4) * 64 + ((q ^ sx)) * 8;
    const int bbase1 = 16384 + (wc * 64 + l4) * 64 + (((4 + q) ^ sx)) * 8;

    f32x4 acc[8][4] = {};
    v8bf abuf[4], bbuf[4];

    // ---- prologue: stage tile 0 fully into buf0 (8 loads), no wait yet ----
    STG_A(0, 0, 0); STG_A(0, 1, 0); STG_B(0, 0, 0); STG_B(0, 1, 0);

    // ---- main loop: 4 lockstep phases per K-tile; vmcnt(2) once per K-tile ----
    for (int t = 0; t < NT - 1; ++t) {
        const int cur = t & 1, nxt = cur ^ 1;
        const int ktn = (t + 1) * 64;
        // ph1: stage A-h0(t+1); retire tile-t's 8 loads; residency barrier; (mh0,kk0)
        STG_A(nxt, 0, ktn);
        VMW(2);
        BAR();
        DSA(cur, abase0, 0); DSB(cur, bbase0);
        MFMA_PH(0);
        // ph2: (mh1,kk0); stage A-h1(t+1)
        DSA(cur, abase0, 1);
        STG_A(nxt, 1, ktn);
        MFMA_PH(1);
        // ph3: (mh0,kk1); stage B-h0(t+1)
        DSA(cur, abase1, 0); DSB(cur, bbase1);
        STG_B(nxt, 0, ktn);
        MFMA_PH(0);
        // ph4: (mh1,kk1); stage B-h1(t+1); trailing BAR (in MFMA_PH) = anti-overwrite fence
        DSA(cur, abase1, 1);
        STG_B(nxt, 1, ktn);
        MFMA_PH(1);
    }
    // ---- peeled last tile: no staging; single drain ----
    {
        const int cur = (NT - 1) & 1;
        VMW(0);
        BAR();
        DSA(cur, abase0, 0); DSB(cur, bbase0);
        MFMA_PH(0);
        DSA(cur, abase0, 1);
        MFMA_PH(1);
        DSA(cur, abase1, 0); DSB(cur, bbase1);
        MFMA_PH(0);
        DSA(cur, abase1, 1);
        MFMA_PH(1);
    }

    // ---- epilogue: C/D layout col=lane&15, row=(lane>>4)*4+j ----
    const int cr = (lane >> 4) * 4;
    const int cc = lane & 15;
    if constexpr (EPI == 0) {
        ushort_t* out = (tn < 2048) ? o0 : (tn < 4096 ? o1 : o2);
        const int nc0 = tn & 2047;
#pragma unroll
        for (int m = 0; m < 8; ++m) {
            const int r0 = tm + wr * 128 + m * 16 + cr;
#pragma unroll
            for (int n = 0; n < 4; ++n) {
                const int c = nc0 + wc * 64 + n * 16 + cc;
#pragma unroll
                for (int j = 0; j < 4; ++j)
                    out[(size_t)(r0 + j) * 2048 + c] = f2b(acc[m][n][j]);
            }
        }
    } else {
#pragma unroll
        for (int m = 0; m < 8; ++m) {
            const int r0 = tm + wr * 128 + m * 16 + cr;
#pragma unroll
            for (int n = 0; n < 4; ++n) {
                const int c = tn + wc * 64 + n * 16 + cc;
#pragma unroll
                for (int j = 0; j < 4; ++j)
                    of[(size_t)(r0 + j) * N + c] = acc[m][n][j];
            }
        }
    }
}

// ---------- retention scan (state_t = lam*state_{t-1} + v_t), chunked 3-pass ----------
__global__ void scan_pass1(const ushort_t* __restrict__ v, const float* __restrict__ beta,
                           float* __restrict__ cf) {
    const int chunk = blockIdx.x, h = blockIdx.y, b = blockIdx.z;
    const int dh = threadIdx.x;   // 128
    const float lam = 1.f / (1.f + __expf(-beta[h]));
    size_t idx = ((size_t)(b * SEQ + chunk * LC) * NHEAD + h) * DHEAD + dh;
    float s = 0.f;
#pragma unroll 4
    for (int l = 0; l < LC; ++l) {
        s = fmaf(s, lam, b2f(v[idx]));
        idx += DMODEL;
    }
    cf[(((size_t)(b * NHEAD + h) * NCH) + chunk) * DHEAD + dh] = s;
}

__global__ void scan_pass2(float* __restrict__ cf, const float* __restrict__ beta) {
    const int t = blockIdx.x * blockDim.x + threadIdx.x;   // B*H*Dh = 8192
    const int dh = t & 127;
    const int bh = t >> 7;          // b*16 + h
    const int h = bh & 15;
    const float lam = 1.f / (1.f + __expf(-beta[h]));
    float lamLc = lam;
#pragma unroll
    for (int i = 0; i < 7; ++i) lamLc *= lamLc;   // lam^128
    float carry = 0.f;
    for (int c = 0; c < NCH; ++c) {
        const size_t i = ((size_t)bh * NCH + c) * DHEAD + dh;
        const float val = cf[i];
        cf[i] = carry;
        carry = fmaf(carry, lamLc, val);
    }
}

__global__ void scan_pass3(const ushort_t* __restrict__ v, const ushort_t* __restrict__ q,
                           const float* __restrict__ beta, const float* __restrict__ cf,
                           ushort_t* __restrict__ y) {
    const int chunk = blockIdx.x, h = blockIdx.y, b = blockIdx.z;
    const int dh = threadIdx.x;
    const float lam = 1.f / (1.f + __expf(-beta[h]));
    float s = cf[(((size_t)(b * NHEAD + h) * NCH) + chunk) * DHEAD + dh];
    size_t idx = ((size_t)(b * SEQ + chunk * LC) * NHEAD + h) * DHEAD + dh;
#pragma unroll 4
    for (int l = 0; l < LC; ++l) {
        s = fmaf(s, lam, b2f(v[idx]));
        y[idx] = f2b(b2f(q[idx]) * s);
        idx += DMODEL;
    }
}

// ---------- rowwise LayerNorm + SiLU gate ----------
__global__ __launch_bounds__(256) void ln_gate(const ushort_t* __restrict__ y,
                                               const ushort_t* g,
                                               const float* __restrict__ lnw,
                                               const float* __restrict__ lnb,
                                               ushort_t* t) {
    const int row = blockIdx.x;
    const int tid = threadIdx.x;
    const size_t base = (size_t)row * DMODEL + tid * 8;

    float yv[8];
    {
        const uint4 raw = *(const uint4*)(y + base);   // 8 bf16
        const ushort_t* p = (const ushort_t*)&raw;
#pragma unroll
        for (int j = 0; j < 8; ++j) yv[j] = b2f(p[j]);
    }
    float s = 0.f, ss = 0.f;
#pragma unroll
    for (int j = 0; j < 8; ++j) { s += yv[j]; ss += yv[j] * yv[j]; }

#pragma unroll
    for (int o = 32; o > 0; o >>= 1) { s += __shfl_down(s, o); ss += __shfl_down(ss, o); }
    __shared__ float red[8];
    const int wid = tid >> 6, lane = tid & 63;
    if (lane == 0) { red[wid] = s; red[4 + wid] = ss; }
    __syncthreads();
    s  = red[0] + red[1] + red[2] + red[3];
    ss = red[4] + red[5] + red[6] + red[7];

    const float mu = s * (1.f / DMODEL);
    const float var = ss * (1.f / DMODEL) - mu * mu;
    const float rs = rsqrtf(var + 1e-5f);

    const int c0 = tid * 8;
    float4 w0 = *(const float4*)(lnw + c0), w1 = *(const float4*)(lnw + c0 + 4);
    float4 b0 = *(const float4*)(lnb + c0), b1 = *(const float4*)(lnb + c0 + 4);
    const float wv[8] = {w0.x, w0.y, w0.z, w0.w, w1.x, w1.y, w1.z, w1.w};
    const float bv[8] = {b0.x, b0.y, b0.z, b0.w, b1.x, b1.y, b1.z, b1.w};

    float gv[8];
    {
        const uint4 raw = *(const uint4*)(g + base);
        const ushort_t* p = (const ushort_t*)&raw;
#pragma unroll
        for (int j = 0; j < 8; ++j) gv[j] = b2f(p[j]);
    }

    ushort_t out[8];
#pragma unroll
    for (int j = 0; j < 8; ++j) {
        const float tv = (yv[j] - mu) * rs * wv[j] + bv[j];
        const float sil = gv[j] / (1.f + __expf(-gv[j]));
        out[j] = f2b(tv * sil);
    }
    *(uint4*)(t + base) = *(const uint4*)out;
}

// ---------- workspace layout (bytes) — TOTAL 161 MiB ----------
#define OFF_XB  ((size_t)0)                         // 64 MiB (xb, later y)
#define OFF_WC  (OFF_XB + (size_t)MROWS*DMODEL*2)   // 24 MiB
#define OFF_WOB (OFF_WC + (size_t)3*DMODEL*DMODEL*2)// 8 MiB
#define OFF_G   (OFF_WOB + (size_t)DMODEL*DMODEL*2) // 64 MiB (g, later t)
#define OFF_CF  (OFF_G + (size_t)MROWS*DMODEL*2)    // 1 MiB
#define OFF_END (OFF_CF + (size_t)BATCH*NHEAD*NCH*DHEAD*4)

extern "C" void kernel_launch(void* const* d_in, const int* in_sizes, int n_in,
                              void* d_out, int out_size, void* d_ws, size_t ws_size,
                              hipStream_t stream) {
    if (ws_size < OFF_END) return;  // refuse to run rather than corrupt adjacent memory

    const float* x    = (const float*)d_in[0];
    const float* Wq   = (const float*)d_in[1];
    const float* Wv   = (const float*)d_in[2];
    const float* Wg   = (const float*)d_in[3];
    const float* Wo   = (const float*)d_in[4];
    const float* beta = (const float*)d_in[5];
    const float* lnw  = (const float*)d_in[6];
    const float* lnb  = (const float*)d_in[7];

    char* ws = (char*)d_ws;
    ushort_t* xb  = (ushort_t*)(ws + OFF_XB);
    ushort_t* Wc  = (ushort_t*)(ws + OFF_WC);
    ushort_t* Wob = (ushort_t*)(ws + OFF_WOB);
    ushort_t* g   = (ushort_t*)(ws + OFF_G);
    float*    cf  = (float*)(ws + OFF_CF);

    ushort_t* q = (ushort_t*)d_out;
    ushort_t* v = q + (size_t)MROWS * DMODEL;
    ushort_t* y = xb;   // xb slab reused after gemm_qvg
    ushort_t* t = g;    // g slab reused by ln_gate (element-wise aliasing)

    const int DD = DMODEL * DMODEL;

    // allow 128 KiB dynamic LDS (idempotent; return value intentionally ignored)
    (void)hipFuncSetAttribute((const void*)gemm8<3 * DMODEL, 0>,
                              hipFuncAttributeMaxDynamicSharedMemorySize, 131072);
    (void)hipFuncSetAttribute((const void*)gemm8<DMODEL, 1>,
                              hipFuncAttributeMaxDynamicSharedMemorySize, 131072);

    cast_f32_bf16<<<2048, 256, 0, stream>>>(x, xb, MROWS * DMODEL);
    cast_weights<<<dim3(256, 4), 256, 0, stream>>>(Wq, Wv, Wg, Wo,
                                                   Wc, Wc + DD, Wc + 2 * DD, Wob);

    // q,v,g = x @ [Wq;Wv;Wg]^T   (M=16384, N=6144, K=2048)
    gemm8<3 * DMODEL, 0><<<(MROWS / 256) * (3 * DMODEL / 256), 512, 131072, stream>>>(
        xb, Wc, q, v, g, nullptr);

    scan_pass1<<<dim3(NCH, NHEAD, BATCH), DHEAD, 0, stream>>>(v, beta, cf);
    scan_pass2<<<(BATCH * NHEAD * DHEAD) / 256, 256, 0, stream>>>(cf, beta);
    scan_pass3<<<dim3(NCH, NHEAD, BATCH), DHEAD, 0, stream>>>(v, q, beta, cf, y);

    ln_gate<<<MROWS, 256, 0, stream>>>(y, g, lnw, lnb, t);

    // out = t @ Wo^T  (M=16384, N=2048, K=2048), fp32 output
    gemm8<DMODEL, 1><<<(MROWS / 256) * (DMODEL / 256), 512, 131072, stream>>>(
        t, Wob, nullptr, nullptr, nullptr, (float*)d_out);
}

// Round 7
// 627.991 us; speedup vs baseline: 1.0288x; 1.0288x over previous
//
#include <hip/hip_runtime.h>

// ---------- sizes (hardcoded for this problem) ----------
#define BATCH 4
#define SEQ   4096
#define DMODEL 2048
#define NHEAD 16
#define DHEAD 128
#define MROWS (BATCH*SEQ)          // 16384
#define LC    128                  // scan chunk length
#define NCH   (SEQ/LC)             // 32 chunks

typedef unsigned short ushort_t;
typedef __bf16 v8bf __attribute__((ext_vector_type(8)));
typedef float  f32x4 __attribute__((ext_vector_type(4)));

__device__ __forceinline__ float b2f(ushort_t h) {
    return __uint_as_float(((unsigned)h) << 16);
}
__device__ __forceinline__ ushort_t f2b(float f) {
    unsigned u = __float_as_uint(f);
    return (ushort_t)((u + 0x7fffu + ((u >> 16) & 1u)) >> 16);
}

// ---------- cast fp32 -> bf16 (8 elem/thread, 16B loads+stores) ----------
__global__ void cast_f32_bf16(const float* __restrict__ in, ushort_t* __restrict__ out, int n) {
    int i = (blockIdx.x * blockDim.x + threadIdx.x) * 8;
    const int stride = gridDim.x * blockDim.x * 8;
    for (; i < n; i += stride) {
        float4 a = *(const float4*)(in + i);
        float4 b = *(const float4*)(in + i + 4);
        ushort_t o[8] = {f2b(a.x), f2b(a.y), f2b(a.z), f2b(a.w),
                         f2b(b.x), f2b(b.y), f2b(b.z), f2b(b.w)};
        *(uint4*)(out + i) = *(const uint4*)o;
    }
}

// 4 weight matrices in one launch (blockIdx.y selects)
__global__ void cast_weights(const float* __restrict__ w0, const float* __restrict__ w1,
                             const float* __restrict__ w2, const float* __restrict__ w3,
                             ushort_t* __restrict__ o0, ushort_t* __restrict__ o1,
                             ushort_t* __restrict__ o2, ushort_t* __restrict__ o3) {
    const int wsel = blockIdx.y;
    const float* src = wsel == 0 ? w0 : wsel == 1 ? w1 : wsel == 2 ? w2 : w3;
    ushort_t* dst    = wsel == 0 ? o0 : wsel == 1 ? o1 : wsel == 2 ? o2 : o3;
    const int n = DMODEL * DMODEL;
    int i = (blockIdx.x * blockDim.x + threadIdx.x) * 8;
    const int stride = gridDim.x * blockDim.x * 8;
    for (; i < n; i += stride) {
        float4 a = *(const float4*)(src + i);
        float4 b = *(const float4*)(src + i + 4);
        ushort_t o[8] = {f2b(a.x), f2b(a.y), f2b(a.z), f2b(a.w),
                         f2b(b.x), f2b(b.y), f2b(b.z), f2b(b.w)};
        *(uint4*)(dst + i) = *(const uint4*)o;
    }
}

// ======== 256x256 bf16 GEMM: conflict-free LDS + compiler-pipelined K-tile body ========
// C = A(MxK) * B(NxK)^T. 512 threads = 8 waves (2M x 4N), per-wave 128x64 out.
// LDS 128 KiB: [2 buf][ A:256x64 | B:256x64 ] bf16, row-major, 128B rows.
// Swizzle: physical 16B-slot-in-row = logical_slot ^ (row & 7) (conflict-free at 16- and
// 32-lane beat granularity). Dest linear, source pre-swizzled (involution both sides).
// Sync: 2 barriers + 1 counted vmcnt(2) per K-tile (round-5 ledger). NO manual lgkmcnt
// drains / sched_barriers: all 24 fragment reads are issued into named register sets ahead
// of their consuming MFMA clusters; the compiler inserts counted lgkmcnt per cluster so
// cluster p's MFMA hides cluster p+1's ds_read latency.

#define GLL(src, dstoff) __builtin_amdgcn_global_load_lds( \
    (const __attribute__((address_space(1))) void*)(src), \
    (__attribute__((address_space(3))) void*)((char*)lds + (dstoff)), 16, 0, 0)

#define STG_A(buf, half, kt) do { \
    GLL(pA + ((half) * 128 +  0) * (size_t)K + (kt), (buf) * 65536 + (half) * 16384 + wid * 1024); \
    GLL(pA + ((half) * 128 + 64) * (size_t)K + (kt), (buf) * 65536 + (half) * 16384 + wid * 1024 + 8192); } while (0)
#define STG_B(buf, half, kt) do { \
    GLL(pB + ((half) * 128 +  0) * (size_t)K + (kt), (buf) * 65536 + 32768 + (half) * 16384 + wid * 1024); \
    GLL(pB + ((half) * 128 + 64) * (size_t)K + (kt), (buf) * 65536 + 32768 + (half) * 16384 + wid * 1024 + 8192); } while (0)

// 4 ds_read_b128 into a named v8bf[4] set (offsets in ushort units; +1024 = 16 rows)
#define DSRD4(dst, off) do { \
    const ushort_t* _p = lds + (off); \
    dst[0] = *(const v8bf*)_p;          dst[1] = *(const v8bf*)(_p + 1024); \
    dst[2] = *(const v8bf*)(_p + 2048); dst[3] = *(const v8bf*)(_p + 3072); } while (0)

#define VMW(n) asm volatile("s_waitcnt vmcnt(" #n ")" ::: "memory")
#define BAR()  __builtin_amdgcn_s_barrier()

// prioritized 16-MFMA cluster; compiler inserts the (counted) lgkmcnt before first use
#define MM(mh, va, vb) do { \
    __builtin_amdgcn_s_setprio(1); \
    _Pragma("unroll") \
    for (int _m = 0; _m < 4; ++_m) \
        _Pragma("unroll") \
        for (int _n = 0; _n < 4; ++_n) \
            acc[(mh) * 4 + _m][_n] = __builtin_amdgcn_mfma_f32_16x16x32_bf16( \
                va[_m], vb[_n], acc[(mh) * 4 + _m][_n], 0, 0, 0); \
    __builtin_amdgcn_s_setprio(0); \
} while (0)

template<int N, int EPI>
__global__ __launch_bounds__(512, 2) void gemm8(const ushort_t* __restrict__ A,
                                                const ushort_t* __restrict__ Bm,
                                                ushort_t* __restrict__ o0,
                                                ushort_t* __restrict__ o1,
                                                ushort_t* __restrict__ o2,
                                                float* __restrict__ of) {
    constexpr int K  = DMODEL;
    constexpr int NT = K / 64;           // 32 K-tiles
    constexpr int NBN = N / 256;
    constexpr int NWG = (MROWS / 256) * NBN;
    extern __shared__ ushort_t lds[];    // 65536 ushorts = 128 KiB

    // XCD-bijective swizzle (NWG % 8 == 0 for both instantiations)
    int wg = blockIdx.x;
    wg = (wg & 7) * (NWG / 8) + (wg >> 3);
    const int tm = (wg / NBN) * 256;
    const int tn = (wg % NBN) * 256;

    const int tid  = threadIdx.x;
    const int lane = tid & 63;
    const int wid  = tid >> 6;           // 8 waves
    const int wr   = wid >> 2;           // 0..1 (M half)
    const int wc   = wid & 3;            // 0..3 (N quarter)

    // ---- staging source base (per-lane, pre-swizzled; dest stays linear) ----
    // dest row = half*128 + j*64 + wid*8 + (lane>>3); phys slot-in-row = lane&7
    // -> logical slot = (lane&7) ^ ((lane>>3)&7)
    const int rs = wid * 8 + (lane >> 3);
    const int cs = ((lane & 7) ^ ((lane >> 3) & 7)) * 8;
    const ushort_t* pA = A  + (size_t)(tm + rs) * K + cs;
    const ushort_t* pB = Bm + (size_t)(tn + rs) * K + cs;

    // ---- fragment ds_read bases (ushort units) ----
    // logical slot = kk*4 + q (q = lane>>4); physical = logical ^ (l4 & 7)
    const int q  = lane >> 4;
    const int l4 = lane & 15;
    const int sx = l4 & 7;
    const int abase0 = (wr * 128 + l4) * 64 + ((q ^ sx)) * 8;
    const int abase1 = (wr * 128 + l4) * 64 + (((4 + q) ^ sx)) * 8;
    const int bbase0 = 16384 + (wc * 64 + l4) * 64 + ((q ^ sx)) * 8;
    const int bbase1 = 16384 + (wc * 64 + l4) * 64 + (((4 + q) ^ sx)) * 8;

    f32x4 acc[8][4] = {};
    v8bf a00[4], a10[4], a01[4], a11[4], b0[4], b1[4];

    // ---- prologue: stage tile 0 fully into buf0 (8 loads), no wait yet ----
    STG_A(0, 0, 0); STG_A(0, 1, 0); STG_B(0, 0, 0); STG_B(0, 1, 0);

    // ---- main loop: pipelined K-tile body; vmcnt(2) + 2 barriers per K-tile ----
    for (int t = 0; t < NT - 1; ++t) {
        const int cur = t & 1, nxt = cur ^ 1;
        const int ktn = (t + 1) * 64;
        const int cb = cur * 32768;
        // staged-before-wait keeps the ledger: 8 old + 2 new -> vmcnt(2) retires the 8
        STG_A(nxt, 0, ktn);
        VMW(2);
        BAR();
        // issue reads ahead; clusters consume in order (compiler emits counted lgkmcnt)
        DSRD4(a00, cb + abase0);          // mh0 kk0
        DSRD4(b0,  cb + bbase0);          // kk0
        DSRD4(a10, cb + abase0 + 4096);   // mh1 kk0
        MM(0, a00, b0);
        STG_A(nxt, 1, ktn);
        DSRD4(a01, cb + abase1);          // mh0 kk1
        DSRD4(b1,  cb + bbase1);          // kk1
        MM(1, a10, b0);
        STG_B(nxt, 0, ktn);
        DSRD4(a11, cb + abase1 + 4096);   // mh1 kk1
        MM(0, a01, b1);
        STG_B(nxt, 1, ktn);
        MM(1, a11, b1);
        BAR();   // anti-overwrite fence (all reads consumed -> lgkmcnt drained by MFMA waits)
    }
    // ---- peeled last tile: no staging; full drain ----
    {
        const int cb = ((NT - 1) & 1) * 32768;
        VMW(0);
        BAR();
        DSRD4(a00, cb + abase0);
        DSRD4(b0,  cb + bbase0);
        DSRD4(a10, cb + abase0 + 4096);
        MM(0, a00, b0);
        DSRD4(a01, cb + abase1);
        DSRD4(b1,  cb + bbase1);
        MM(1, a10, b0);
        DSRD4(a11, cb + abase1 + 4096);
        MM(0, a01, b1);
        MM(1, a11, b1);
    }

    // ---- epilogue: C/D layout col=lane&15, row=(lane>>4)*4+j ----
    const int cr = (lane >> 4) * 4;
    const int cc = lane & 15;
    if constexpr (EPI == 0) {
        ushort_t* out = (tn < 2048) ? o0 : (tn < 4096 ? o1 : o2);
        const int nc0 = tn & 2047;
#pragma unroll
        for (int m = 0; m < 8; ++m) {
            const int r0 = tm + wr * 128 + m * 16 + cr;
#pragma unroll
            for (int n = 0; n < 4; ++n) {
                const int c = nc0 + wc * 64 + n * 16 + cc;
#pragma unroll
                for (int j = 0; j < 4; ++j)
                    out[(size_t)(r0 + j) * 2048 + c] = f2b(acc[m][n][j]);
            }
        }
    } else {
#pragma unroll
        for (int m = 0; m < 8; ++m) {
            const int r0 = tm + wr * 128 + m * 16 + cr;
#pragma unroll
            for (int n = 0; n < 4; ++n) {
                const int c = tn + wc * 64 + n * 16 + cc;
#pragma unroll
                for (int j = 0; j < 4; ++j)
                    of[(size_t)(r0 + j) * N + c] = acc[m][n][j];
            }
        }
    }
}

// ---------- retention scan (state_t = lam*state_{t-1} + v_t), chunked 3-pass ----------
__global__ void scan_pass1(const ushort_t* __restrict__ v, const float* __restrict__ beta,
                           float* __restrict__ cf) {
    const int chunk = blockIdx.x, h = blockIdx.y, b = blockIdx.z;
    const int dh = threadIdx.x;   // 128
    const float lam = 1.f / (1.f + __expf(-beta[h]));
    size_t idx = ((size_t)(b * SEQ + chunk * LC) * NHEAD + h) * DHEAD + dh;
    float s = 0.f;
#pragma unroll 4
    for (int l = 0; l < LC; ++l) {
        s = fmaf(s, lam, b2f(v[idx]));
        idx += DMODEL;
    }
    cf[(((size_t)(b * NHEAD + h) * NCH) + chunk) * DHEAD + dh] = s;
}

__global__ void scan_pass2(float* __restrict__ cf, const float* __restrict__ beta) {
    const int t = blockIdx.x * blockDim.x + threadIdx.x;   // B*H*Dh = 8192
    const int dh = t & 127;
    const int bh = t >> 7;          // b*16 + h
    const int h = bh & 15;
    const float lam = 1.f / (1.f + __expf(-beta[h]));
    float lamLc = lam;
#pragma unroll
    for (int i = 0; i < 7; ++i) lamLc *= lamLc;   // lam^128
    float carry = 0.f;
    for (int c = 0; c < NCH; ++c) {
        const size_t i = ((size_t)bh * NCH + c) * DHEAD + dh;
        const float val = cf[i];
        cf[i] = carry;
        carry = fmaf(carry, lamLc, val);
    }
}

__global__ void scan_pass3(const ushort_t* __restrict__ v, const ushort_t* __restrict__ q,
                           const float* __restrict__ beta, const float* __restrict__ cf,
                           ushort_t* __restrict__ y) {
    const int chunk = blockIdx.x, h = blockIdx.y, b = blockIdx.z;
    const int dh = threadIdx.x;
    const float lam = 1.f / (1.f + __expf(-beta[h]));
    float s = cf[(((size_t)(b * NHEAD + h) * NCH) + chunk) * DHEAD + dh];
    size_t idx = ((size_t)(b * SEQ + chunk * LC) * NHEAD + h) * DHEAD + dh;
#pragma unroll 4
    for (int l = 0; l < LC; ++l) {
        s = fmaf(s, lam, b2f(v[idx]));
        y[idx] = f2b(b2f(q[idx]) * s);
        idx += DMODEL;
    }
}

// ---------- rowwise LayerNorm + SiLU gate ----------
__global__ __launch_bounds__(256) void ln_gate(const ushort_t* __restrict__ y,
                                               const ushort_t* g,
                                               const float* __restrict__ lnw,
                                               const float* __restrict__ lnb,
                                               ushort_t* t) {
    const int row = blockIdx.x;
    const int tid = threadIdx.x;
    const size_t base = (size_t)row * DMODEL + tid * 8;

    float yv[8];
    {
        const uint4 raw = *(const uint4*)(y + base);   // 8 bf16
        const ushort_t* p = (const ushort_t*)&raw;
#pragma unroll
        for (int j = 0; j < 8; ++j) yv[j] = b2f(p[j]);
    }
    float s = 0.f, ss = 0.f;
#pragma unroll
    for (int j = 0; j < 8; ++j) { s += yv[j]; ss += yv[j] * yv[j]; }

#pragma unroll
    for (int o = 32; o > 0; o >>= 1) { s += __shfl_down(s, o); ss += __shfl_down(ss, o); }
    __shared__ float red[8];
    const int wid = tid >> 6, lane = tid & 63;
    if (lane == 0) { red[wid] = s; red[4 + wid] = ss; }
    __syncthreads();
    s  = red[0] + red[1] + red[2] + red[3];
    ss = red[4] + red[5] + red[6] + red[7];

    const float mu = s * (1.f / DMODEL);
    const float var = ss * (1.f / DMODEL) - mu * mu;
    const float rs = rsqrtf(var + 1e-5f);

    const int c0 = tid * 8;
    float4 w0 = *(const float4*)(lnw + c0), w1 = *(const float4*)(lnw + c0 + 4);
    float4 b0 = *(const float4*)(lnb + c0), b1 = *(const float4*)(lnb + c0 + 4);
    const float wv[8] = {w0.x, w0.y, w0.z, w0.w, w1.x, w1.y, w1.z, w1.w};
    const float bv[8] = {b0.x, b0.y, b0.z, b0.w, b1.x, b1.y, b1.z, b1.w};

    float gv[8];
    {
        const uint4 raw = *(const uint4*)(g + base);
        const ushort_t* p = (const ushort_t*)&raw;
#pragma unroll
        for (int j = 0; j < 8; ++j) gv[j] = b2f(p[j]);
    }

    ushort_t out[8];
#pragma unroll
    for (int j = 0; j < 8; ++j) {
        const float tv = (yv[j] - mu) * rs * wv[j] + bv[j];
        const float sil = gv[j] / (1.f + __expf(-gv[j]));
        out[j] = f2b(tv * sil);
    }
    *(uint4*)(t + base) = *(const uint4*)out;
}

// ---------- workspace layout (bytes) — TOTAL 161 MiB ----------
#define OFF_XB  ((size_t)0)                         // 64 MiB (xb, later y)
#define OFF_WC  (OFF_XB + (size_t)MROWS*DMODEL*2)   // 24 MiB
#define OFF_WOB (OFF_WC + (size_t)3*DMODEL*DMODEL*2)// 8 MiB
#define OFF_G   (OFF_WOB + (size_t)DMODEL*DMODEL*2) // 64 MiB (g, later t)
#define OFF_CF  (OFF_G + (size_t)MROWS*DMODEL*2)    // 1 MiB
#define OFF_END (OFF_CF + (size_t)BATCH*NHEAD*NCH*DHEAD*4)

extern "C" void kernel_launch(void* const* d_in, const int* in_sizes, int n_in,
                              void* d_out, int out_size, void* d_ws, size_t ws_size,
                              hipStream_t stream) {
    if (ws_size < OFF_END) return;  // refuse to run rather than corrupt adjacent memory

    const float* x    = (const float*)d_in[0];
    const float* Wq   = (const float*)d_in[1];
    const float* Wv   = (const float*)d_in[2];
    const float* Wg   = (const float*)d_in[3];
    const float* Wo   = (const float*)d_in[4];
    const float* beta = (const float*)d_in[5];
    const float* lnw  = (const float*)d_in[6];
    const float* lnb  = (const float*)d_in[7];

    char* ws = (char*)d_ws;
    ushort_t* xb  = (ushort_t*)(ws + OFF_XB);
    ushort_t* Wc  = (ushort_t*)(ws + OFF_WC);
    ushort_t* Wob = (ushort_t*)(ws + OFF_WOB);
    ushort_t* g   = (ushort_t*)(ws + OFF_G);
    float*    cf  = (float*)(ws + OFF_CF);

    ushort_t* q = (ushort_t*)d_out;
    ushort_t* v = q + (size_t)MROWS * DMODEL;
    ushort_t* y = xb;   // xb slab reused after gemm_qvg
    ushort_t* t = g;    // g slab reused by ln_gate (element-wise aliasing)

    const int DD = DMODEL * DMODEL;

    // allow 128 KiB dynamic LDS (idempotent; return value intentionally ignored)
    (void)hipFuncSetAttribute((const void*)gemm8<3 * DMODEL, 0>,
                              hipFuncAttributeMaxDynamicSharedMemorySize, 131072);
    (void)hipFuncSetAttribute((const void*)gemm8<DMODEL, 1>,
                              hipFuncAttributeMaxDynamicSharedMemorySize, 131072);

    cast_f32_bf16<<<2048, 256, 0, stream>>>(x, xb, MROWS * DMODEL);
    cast_weights<<<dim3(256, 4), 256, 0, stream>>>(Wq, Wv, Wg, Wo,
                                                   Wc, Wc + DD, Wc + 2 * DD, Wob);

    // q,v,g = x @ [Wq;Wv;Wg]^T   (M=16384, N=6144, K=2048)
    gemm8<3 * DMODEL, 0><<<(MROWS / 256) * (3 * DMODEL / 256), 512, 131072, stream>>>(
        xb, Wc, q, v, g, nullptr);

    scan_pass1<<<dim3(NCH, NHEAD, BATCH), DHEAD, 0, stream>>>(v, beta, cf);
    scan_pass2<<<(BATCH * NHEAD * DHEAD) / 256, 256, 0, stream>>>(cf, beta);
    scan_pass3<<<dim3(NCH, NHEAD, BATCH), DHEAD, 0, stream>>>(v, q, beta, cf, y);

    ln_gate<<<MROWS, 256, 0, stream>>>(y, g, lnw, lnb, t);

    // out = t @ Wo^T  (M=16384, N=2048, K=2048), fp32 output
    gemm8<DMODEL, 1><<<(MROWS / 256) * (DMODEL / 256), 512, 131072, stream>>>(
        t, Wob, nullptr, nullptr, nullptr, (float*)d_out);
}